// Round 1
// 417.784 us; speedup vs baseline: 1.0443x; 1.0443x over previous
//
#include <hip/hip_runtime.h>

// SpectralLayerNorm: complex (2-channel) layer norm with 2x2 whitening.
// x: (B,S,D,2) fp32, gamma: (D,3), beta: (D,2), out fp32.
//
// Round 1 restructure: BLOCK per token (was: wave per token).
//  - 256 threads share one token: 4 float4/thread instead of 16/lane.
//    x-registers drop 64 -> 16 VGPRs; with beta hoisted (16 more) the
//    kernel targets <=64 VGPRs => 8 waves/SIMD (was ~2 at >128 VGPRs).
//  - Moment reduction: 6-step wave butterfly + 80 B LDS exchange + one
//    __syncthreads (4 partials x 5 sums), broadcast reads.
//  - Nontemporal load/store on the two 268 MB single-use streams; beta
//    (16 KB) and gamma (24 KB) stay cached (gamma is block-uniform ->
//    scalar loads).
// Analytical folds (unchanged, verified vs reference):
//  - A^{-1/2} of SPD 2x2: s=sqrt(det), t=sqrt(tr+2s),
//    A^{-1/2} = [[c+s,-b],[-b,a+s]]/(s*t)
//  - Gt[k'] = G[k' % d], k' = dd*bs + tok, bs % d == 0 => G[tok % d];
//    folded into whitening: M = G @ A^{-1/2}
//  - one-pass raw moments: cov = (Sxy - Sx*mu_y)/(D-1), EPS on diagonal.

typedef float f32x4 __attribute__((ext_vector_type(4)));

constexpr int D = 2048;
constexpr float EPSV = 1e-5f;

__global__ __launch_bounds__(256, 8)
void spectral_ln_kernel(const f32x4* __restrict__ x4,
                        const float* __restrict__ gamma,
                        const f32x4* __restrict__ beta4,
                        f32x4* __restrict__ out4)
{
    __shared__ float red[4][5];

    const int tid  = threadIdx.x;
    const int lane = tid & 63;
    const int wid  = tid >> 6;
    const int tok  = blockIdx.x;
    const long base = (long)tok * (D * 2 / 4);   // 1024 f32x4 per token

    const f32x4* __restrict__ xin = x4 + base;

    // 4 fully-coalesced 256-thread streaming loads (single-use -> nt),
    // beta hoisted up front so the epilogue is load-free.
    f32x4 v[4], bt[4];
#pragma unroll
    for (int j = 0; j < 4; ++j)
        v[j] = __builtin_nontemporal_load(xin + j * 256 + tid);
#pragma unroll
    for (int j = 0; j < 4; ++j)
        bt[j] = beta4[j * 256 + tid];

    // ---- one-pass raw moments over this thread's 8 complex elements ----
    float sr = 0.f, si = 0.f, rr = 0.f, ri = 0.f, ii = 0.f;
#pragma unroll
    for (int j = 0; j < 4; ++j) {
        sr += v[j].x + v[j].z;  si += v[j].y + v[j].w;
        rr += v[j].x * v[j].x + v[j].z * v[j].z;
        ri += v[j].x * v[j].y + v[j].z * v[j].w;
        ii += v[j].y * v[j].y + v[j].w * v[j].w;
    }
    // wave butterfly: every lane ends with its wave's partial sums
#pragma unroll
    for (int o = 32; o > 0; o >>= 1) {
        sr += __shfl_xor(sr, o, 64);
        si += __shfl_xor(si, o, 64);
        rr += __shfl_xor(rr, o, 64);
        ri += __shfl_xor(ri, o, 64);
        ii += __shfl_xor(ii, o, 64);
    }
    // cross-wave exchange: 80 B LDS, one barrier, broadcast reads
    if (lane == 0) {
        red[wid][0] = sr; red[wid][1] = si; red[wid][2] = rr;
        red[wid][3] = ri; red[wid][4] = ii;
    }
    __syncthreads();
    sr = red[0][0] + red[1][0] + red[2][0] + red[3][0];
    si = red[0][1] + red[1][1] + red[2][1] + red[3][1];
    rr = red[0][2] + red[1][2] + red[2][2] + red[3][2];
    ri = red[0][3] + red[1][3] + red[2][3] + red[3][3];
    ii = red[0][4] + red[1][4] + red[2][4] + red[3][4];

    const float invD = 1.0f / D, inv_dm1 = 1.0f / (D - 1);
    const float mu_r = sr * invD, mu_i = si * invD;
    const float a = (rr - sr * mu_r) * inv_dm1 + EPSV;   // Srr - D*mu_r^2
    const float b = (ri - sr * mu_i) * inv_dm1;          // Sri - D*mu_r*mu_i
    const float c = (ii - si * mu_i) * inv_dm1 + EPSV;

    // ---- closed-form symmetric inverse sqrt of [[a,b],[b,c]] ----
    const float s   = sqrtf(a * c - b * b);
    const float t2  = sqrtf(a + c + 2.f * s);
    const float inv = 1.f / (s * t2);
    const float si00 = (c + s) * inv, si01 = -b * inv, si11 = (a + s) * inv;

    // ---- fold token-indexed gamma (block-uniform -> scalar loads) ----
    const int m = tok & (D - 1);
    const float g0 = gamma[m * 3 + 0], g1 = gamma[m * 3 + 1], g2 = gamma[m * 3 + 2];
    const float M00 = g0 * si00 + g1 * si01;
    const float M01 = g0 * si01 + g1 * si11;
    const float M10 = g1 * si00 + g2 * si01;
    const float M11 = g1 * si01 + g2 * si11;

    // ---- center, transform, add beta; load-free epilogue, nt stores ----
    f32x4* __restrict__ op = out4 + base;
#pragma unroll
    for (int j = 0; j < 4; ++j) {
        const float cr0 = v[j].x - mu_r, ci0 = v[j].y - mu_i;
        const float cr1 = v[j].z - mu_r, ci1 = v[j].w - mu_i;
        f32x4 o4;
        o4.x = M00 * cr0 + M01 * ci0 + bt[j].x;
        o4.y = M10 * cr0 + M11 * ci0 + bt[j].y;
        o4.z = M00 * cr1 + M01 * ci1 + bt[j].z;
        o4.w = M10 * cr1 + M11 * ci1 + bt[j].w;
        __builtin_nontemporal_store(o4, op + j * 256 + tid);
    }
}

extern "C" void kernel_launch(void* const* d_in, const int* in_sizes, int n_in,
                              void* d_out, int out_size, void* d_ws, size_t ws_size,
                              hipStream_t stream) {
    const f32x4* x4    = (const f32x4*)d_in[0];
    const float* gamma = (const float*)d_in[1];
    const f32x4* beta4 = (const f32x4*)d_in[2];
    f32x4* out4 = (f32x4*)d_out;
    const int n_tokens = in_sizes[0] / (D * 2);    // B*S = 16384
    spectral_ln_kernel<<<dim3(n_tokens), dim3(256), 0, stream>>>(x4, gamma, beta4, out4);
}